// Round 11
// baseline (20.837 us; speedup 1.0000x reference)
//
#include <hip/hip_runtime.h>

// Bidirectional Chamfer distance, fp32, (16, 2048, 3) — MFMA formulation.
//
// One pairwise matrix serves BOTH directions: D[i][j] = pp_i + tt_j - 2 p.t;
// row-min over j = pred->tgt mins, col-min over i = tgt->pred mins.
//
// Precision: split-bf16. Each fp32 value v = hi + lo (bf16 RNE pair), error
// ~2^-17 rel. K=16 of mfma_f32_32x32x16_bf16 packs the WHOLE d2:
//   k0-2 : A=Phi ,  B=Thi     (Phi = split hi of -2p)
//   k3-5 : A=Plo ,  B=Thi
//   k6-8 : A=Phi ,  B=Tlo
//   k9-11: A=Plo ,  B=Tlo
//   k12  : A=pp_hi, B=1        k13: A=pp_lo, B=1
//   k14  : A=1,     B=tt_hi    k15: A=1,     B=tt_lo
// -> accumulator IS d2; epilogue is pure min-folding.
//
// chamfer: 256 blocks = batch(16) x row-strip(16 of 128 pred rows),
//   512 thr = 8 waves. Wave w: rows (w&3)*32 of the strip, col-half w>>2
//   (32 col-tiles of 32 tgt points). A-frag (4 VGPR) fixed per lane; B-frags
//   staged in LDS (64 KB) in exact fragment order -> 1 ds_read_b128/tile.
//   Per tile: 1 MFMA + 16 rowmin-min + 15-min col-fold + shfl_xor(32).
//   C/D layout (verified): col=lane&31, row=(reg&3)+8*(reg>>2)+4*(lane>>5).
//   Outputs: colmin partial [2048] -> ws, rowsum (sum of 128 full rowmins,
//   pp/tt already inside) -> ws. Block 0 zeroes out[0] (read only by node 2).
// reduce: 256 blocks = batch x col-chunk(128): min over 16 strips, sum,
//   + one rowsum entry, one scaled atomicAdd into out[0].

typedef __attribute__((ext_vector_type(8)))  short s16x8;
typedef __attribute__((ext_vector_type(16))) float f32x16;

#define NPTS   2048
#define BATCH  16
#define MSTRIP 128
#define NSTRIP 16
#define NBLK   256
#define SCALE  (1.0f / 32768.0f)

__device__ __forceinline__ unsigned short bf16_rne(float f) {
    unsigned int u = __float_as_uint(f);
    return (unsigned short)((u + 0x7fffu + ((u >> 16) & 1u)) >> 16);
}
__device__ __forceinline__ float bf16_up(unsigned short h) {
    return __uint_as_float(((unsigned int)h) << 16);
}
__device__ __forceinline__ void split(float v, unsigned short& hi, unsigned short& lo) {
    hi = bf16_rne(v);
    lo = bf16_rne(v - bf16_up(hi));
}

__global__ __launch_bounds__(512) void chamfer_kernel(
    const float* __restrict__ pred,
    const float* __restrict__ tgt,
    float* __restrict__ wscol,     // [NBLK][NPTS] colmin partials
    float* __restrict__ wsrow,     // [NBLK] rowsum partials
    float* __restrict__ out)
{
    const int bid   = blockIdx.x;
    const int b     = bid >> 4;
    const int strip = bid & 15;
    const int tid   = threadIdx.x;
    const int w  = tid >> 6, l = tid & 63;
    const int cl = l & 31, g = l >> 5, h = w >> 2;

    if (bid == 0 && tid == 0) out[0] = 0.0f;   // read only by reduce node

    const float* Pb = pred + (size_t)b * NPTS * 3;
    const float* Tb = tgt  + (size_t)b * NPTS * 3;

    __shared__ s16x8 bfr[NPTS * 2];        // 64 KB B-fragments
    __shared__ float colpart[4][NPTS];     // 32 KB per-wave-row col partials
    __shared__ float rowpart[8][2][16];
    __shared__ float rsum_s[8];

    const unsigned short ONE = 0x3f80;     // bf16 1.0

    // --- Stage T as ready-to-read B-fragments (4 points per thread) ---
    {
        const float4* T4 = (const float4*)Tb;
        const float4 va = T4[tid * 3 + 0];
        const float4 vb = T4[tid * 3 + 1];
        const float4 vc = T4[tid * 3 + 2];
        const float xs[4] = {va.x, va.w, vb.z, vc.y};
        const float ys[4] = {va.y, vb.x, vb.w, vc.z};
        const float zs[4] = {va.z, vb.y, vc.x, vc.w};
        #pragma unroll
        for (int k = 0; k < 4; ++k) {
            const int c = tid * 4 + k;
            unsigned short hx, lx, hy, ly, hz, lz, th_, tl_;
            split(xs[k], hx, lx); split(ys[k], hy, ly); split(zs[k], hz, lz);
            const float tt = xs[k]*xs[k] + ys[k]*ys[k] + zs[k]*zs[k];
            split(tt, th_, tl_);
            s16x8 b0, b1;
            b0[0]=(short)hx; b0[1]=(short)hy; b0[2]=(short)hz; b0[3]=(short)hx;
            b0[4]=(short)hy; b0[5]=(short)hz; b0[6]=(short)lx; b0[7]=(short)ly;
            b1[0]=(short)lz; b1[1]=(short)lx; b1[2]=(short)ly; b1[3]=(short)lz;
            b1[4]=(short)ONE; b1[5]=(short)ONE; b1[6]=(short)th_; b1[7]=(short)tl_;
            bfr[(c >> 5) * 64 +      (c & 31)] = b0;   // k-group 0
            bfr[(c >> 5) * 64 + 32 + (c & 31)] = b1;   // k-group 1
        }
    }

    // --- A-fragment: my pred row (row = lane&31 of this wave's 32-row set) ---
    float rowmin[16];
    #pragma unroll
    for (int r = 0; r < 16; ++r) rowmin[r] = 3.4e38f;

    s16x8 af;
    {
        const int grow = strip * MSTRIP + (w & 3) * 32 + cl;
        const float x = Pb[grow * 3 + 0];
        const float y = Pb[grow * 3 + 1];
        const float z = Pb[grow * 3 + 2];
        const float ax = -2.0f * x, ay = -2.0f * y, az = -2.0f * z;
        const float pp = x * x + y * y + z * z;
        unsigned short phx, plx, phy, ply, phz, plz, pph, ppl;
        split(ax, phx, plx); split(ay, phy, ply); split(az, phz, plz);
        split(pp, pph, ppl);
        s16x8 a0, a1;
        a0[0]=(short)phx; a0[1]=(short)phy; a0[2]=(short)phz; a0[3]=(short)plx;
        a0[4]=(short)ply; a0[5]=(short)plz; a0[6]=(short)phx; a0[7]=(short)phy;
        a1[0]=(short)phz; a1[1]=(short)plx; a1[2]=(short)ply; a1[3]=(short)plz;
        a1[4]=(short)pph; a1[5]=(short)ppl; a1[6]=(short)ONE; a1[7]=(short)ONE;
        af = g ? a1 : a0;
    }

    __syncthreads();

    f32x16 zacc;
    #pragma unroll
    for (int r = 0; r < 16; ++r) zacc[r] = 0.0f;

    // --- 32 col-tiles: 1 MFMA + min-folding each ---
    #pragma unroll 2
    for (int t = 0; t < 32; ++t) {
        const int gt = h * 32 + t;
        const s16x8 bf = bfr[gt * 64 + l];
        f32x16 acc = __builtin_amdgcn_mfma_f32_32x32x16_bf16(af, bf, zacc, 0, 0, 0);
        #pragma unroll
        for (int r = 0; r < 16; ++r) rowmin[r] = fminf(rowmin[r], acc[r]);
        const float c01 = fminf(acc[0], acc[1]),  c23 = fminf(acc[2], acc[3]);
        const float c45 = fminf(acc[4], acc[5]),  c67 = fminf(acc[6], acc[7]);
        const float c89 = fminf(acc[8], acc[9]),  cab = fminf(acc[10], acc[11]);
        const float ccd = fminf(acc[12], acc[13]), cef = fminf(acc[14], acc[15]);
        float colv = fminf(fminf(fminf(c01, c23), fminf(c45, c67)),
                           fminf(fminf(c89, cab), fminf(ccd, cef)));
        colv = fminf(colv, __shfl_xor(colv, 32));       // other 16 rows
        colpart[w & 3][gt * 32 + cl] = colv;            // dup write l/l+32: benign
    }

    // --- rowmin: reduce over the 32 cols held across lanes of my k-group ---
    #pragma unroll
    for (int mask = 1; mask < 32; mask <<= 1) {
        #pragma unroll
        for (int r = 0; r < 16; ++r)
            rowmin[r] = fminf(rowmin[r], __shfl_xor(rowmin[r], mask));
    }
    if (cl == 0) {
        #pragma unroll
        for (int r = 0; r < 16; ++r) rowpart[w][g][r] = rowmin[r];
    }
    __syncthreads();

    // --- rowsum: min across col-halves (w vs w+4), sum 128 rows ---
    if (tid < MSTRIP) {
        const int sub = tid >> 5, rr = tid & 31;
        const int gg = (rr >> 2) & 1, reg = (rr & 3) | ((rr >> 3) << 2);
        float v = fminf(rowpart[sub][gg][reg], rowpart[sub + 4][gg][reg]);
        #pragma unroll
        for (int off = 32; off > 0; off >>= 1) v += __shfl_down(v, off);
        if ((tid & 63) == 0) rsum_s[tid >> 6] = v;
    }

    // --- colmin: min across the 4 wave-row-groups, store to ws ---
    {
        const float4* c0 = (const float4*)colpart[0];
        const float4* c1 = (const float4*)colpart[1];
        const float4* c2 = (const float4*)colpart[2];
        const float4* c3 = (const float4*)colpart[3];
        const float4 v0 = c0[tid], v1 = c1[tid], v2 = c2[tid], v3 = c3[tid];
        float4 o;
        o.x = fminf(fminf(v0.x, v1.x), fminf(v2.x, v3.x));
        o.y = fminf(fminf(v0.y, v1.y), fminf(v2.y, v3.y));
        o.z = fminf(fminf(v0.z, v1.z), fminf(v2.z, v3.z));
        o.w = fminf(fminf(v0.w, v1.w), fminf(v2.w, v3.w));
        ((float4*)(wscol + (size_t)bid * NPTS))[tid] = o;
    }
    __syncthreads();
    if (tid == 0) wsrow[bid] = rsum_s[0] + rsum_s[1];
}

// reduce: block g -> batch g>>4, cols [(g&15)*128, +128): min over 16 strips,
// sum 128 cols, add rowsum entry g, one scaled atomicAdd.
__global__ __launch_bounds__(128) void reduce_kernel(
    const float* __restrict__ wscol,
    const float* __restrict__ wsrow,
    float* __restrict__ out)
{
    const int gblk = blockIdx.x;
    const int bb = gblk >> 4, cc = gblk & 15;
    const int tid = threadIdx.x;
    __shared__ float s2[2];

    const float* base = wscol + (size_t)bb * NSTRIP * NPTS + cc * 128 + tid;
    float m = base[0];
    #pragma unroll
    for (int s = 1; s < 16; ++s) m = fminf(m, base[(size_t)s * NPTS]);

    #pragma unroll
    for (int off = 32; off > 0; off >>= 1) m += __shfl_down(m, off);
    if ((tid & 63) == 0) s2[tid >> 6] = m;
    __syncthreads();
    if (tid == 0)
        atomicAdd(out, (s2[0] + s2[1] + wsrow[gblk]) * SCALE);
}

extern "C" void kernel_launch(void* const* d_in, const int* in_sizes, int n_in,
                              void* d_out, int out_size, void* d_ws, size_t ws_size,
                              hipStream_t stream)
{
    const float* pred = (const float*)d_in[0];
    const float* tgt  = (const float*)d_in[1];
    float* out   = (float*)d_out;
    float* wscol = (float*)d_ws;                             // 2 MB
    float* wsrow = (float*)d_ws + (size_t)NBLK * NPTS;       // 256 floats

    chamfer_kernel<<<dim3(NBLK), dim3(512), 0, stream>>>(pred, tgt, wscol, wsrow, out);
    reduce_kernel<<<dim3(NBLK), dim3(128), 0, stream>>>(wscol, wsrow, out);
}

// Round 12
// 18.446 us; speedup vs baseline: 1.1296x; 1.1296x over previous
//
#include <hip/hip_runtime.h>

// Bidirectional Chamfer distance, fp32, (16, 2048, 3) — MFMA formulation.
//
// R12 = R11's chamfer kernel VERBATIM (passed, absmax 0.0) + lean reduce:
//   64 blocks = batch(16) x col-chunk(4 of 512 cols); coalesced float4
//   reads (32 KB/block), min over 16 strips, sum over 512 cols, + 4 rowsum
//   entries, ONE atomicAdd per block (64 same-address atomics vs R11's 256).
//
// D[i][j] = pp_i + tt_j - 2 p.t serves both directions: row-min = pred->tgt,
// col-min = tgt->pred. Split-bf16 (v = hi + lo) with the whole affine d2
// packed into K=16 of mfma_f32_32x32x16_bf16:
//   k0-2: Phi*Thi  k3-5: Plo*Thi  k6-8: Phi*Tlo  k9-11: Plo*Tlo
//   k12: pp_hi*1   k13: pp_lo*1   k14: 1*tt_hi   k15: 1*tt_lo
// -> accumulator IS d2; epilogue is pure min-folding.

typedef __attribute__((ext_vector_type(8)))  short s16x8;
typedef __attribute__((ext_vector_type(16))) float f32x16;

#define NPTS   2048
#define BATCH  16
#define MSTRIP 128
#define NSTRIP 16
#define NBLK   256
#define SCALE  (1.0f / 32768.0f)

__device__ __forceinline__ unsigned short bf16_rne(float f) {
    unsigned int u = __float_as_uint(f);
    return (unsigned short)((u + 0x7fffu + ((u >> 16) & 1u)) >> 16);
}
__device__ __forceinline__ float bf16_up(unsigned short h) {
    return __uint_as_float(((unsigned int)h) << 16);
}
__device__ __forceinline__ void split(float v, unsigned short& hi, unsigned short& lo) {
    hi = bf16_rne(v);
    lo = bf16_rne(v - bf16_up(hi));
}

__global__ __launch_bounds__(512) void chamfer_kernel(
    const float* __restrict__ pred,
    const float* __restrict__ tgt,
    float* __restrict__ wscol,     // [NBLK][NPTS] colmin partials
    float* __restrict__ wsrow,     // [NBLK] rowsum partials
    float* __restrict__ out)
{
    const int bid   = blockIdx.x;
    const int b     = bid >> 4;
    const int strip = bid & 15;
    const int tid   = threadIdx.x;
    const int w  = tid >> 6, l = tid & 63;
    const int cl = l & 31, g = l >> 5, h = w >> 2;

    if (bid == 0 && tid == 0) out[0] = 0.0f;   // read only by reduce node

    const float* Pb = pred + (size_t)b * NPTS * 3;
    const float* Tb = tgt  + (size_t)b * NPTS * 3;

    __shared__ s16x8 bfr[NPTS * 2];        // 64 KB B-fragments
    __shared__ float colpart[4][NPTS];     // 32 KB per-wave-row col partials
    __shared__ float rowpart[8][2][16];
    __shared__ float rsum_s[8];

    const unsigned short ONE = 0x3f80;     // bf16 1.0

    // --- Stage T as ready-to-read B-fragments (4 points per thread) ---
    {
        const float4* T4 = (const float4*)Tb;
        const float4 va = T4[tid * 3 + 0];
        const float4 vb = T4[tid * 3 + 1];
        const float4 vc = T4[tid * 3 + 2];
        const float xs[4] = {va.x, va.w, vb.z, vc.y};
        const float ys[4] = {va.y, vb.x, vb.w, vc.z};
        const float zs[4] = {va.z, vb.y, vc.x, vc.w};
        #pragma unroll
        for (int k = 0; k < 4; ++k) {
            const int c = tid * 4 + k;
            unsigned short hx, lx, hy, ly, hz, lz, th_, tl_;
            split(xs[k], hx, lx); split(ys[k], hy, ly); split(zs[k], hz, lz);
            const float tt = xs[k]*xs[k] + ys[k]*ys[k] + zs[k]*zs[k];
            split(tt, th_, tl_);
            s16x8 b0, b1;
            b0[0]=(short)hx; b0[1]=(short)hy; b0[2]=(short)hz; b0[3]=(short)hx;
            b0[4]=(short)hy; b0[5]=(short)hz; b0[6]=(short)lx; b0[7]=(short)ly;
            b1[0]=(short)lz; b1[1]=(short)lx; b1[2]=(short)ly; b1[3]=(short)lz;
            b1[4]=(short)ONE; b1[5]=(short)ONE; b1[6]=(short)th_; b1[7]=(short)tl_;
            bfr[(c >> 5) * 64 +      (c & 31)] = b0;   // k-group 0
            bfr[(c >> 5) * 64 + 32 + (c & 31)] = b1;   // k-group 1
        }
    }

    // --- A-fragment: my pred row (row = lane&31 of this wave's 32-row set) ---
    float rowmin[16];
    #pragma unroll
    for (int r = 0; r < 16; ++r) rowmin[r] = 3.4e38f;

    s16x8 af;
    {
        const int grow = strip * MSTRIP + (w & 3) * 32 + cl;
        const float x = Pb[grow * 3 + 0];
        const float y = Pb[grow * 3 + 1];
        const float z = Pb[grow * 3 + 2];
        const float ax = -2.0f * x, ay = -2.0f * y, az = -2.0f * z;
        const float pp = x * x + y * y + z * z;
        unsigned short phx, plx, phy, ply, phz, plz, pph, ppl;
        split(ax, phx, plx); split(ay, phy, ply); split(az, phz, plz);
        split(pp, pph, ppl);
        s16x8 a0, a1;
        a0[0]=(short)phx; a0[1]=(short)phy; a0[2]=(short)phz; a0[3]=(short)plx;
        a0[4]=(short)ply; a0[5]=(short)plz; a0[6]=(short)phx; a0[7]=(short)phy;
        a1[0]=(short)phz; a1[1]=(short)plx; a1[2]=(short)ply; a1[3]=(short)plz;
        a1[4]=(short)pph; a1[5]=(short)ppl; a1[6]=(short)ONE; a1[7]=(short)ONE;
        af = g ? a1 : a0;
    }

    __syncthreads();

    f32x16 zacc;
    #pragma unroll
    for (int r = 0; r < 16; ++r) zacc[r] = 0.0f;

    // --- 32 col-tiles: 1 MFMA + min-folding each ---
    #pragma unroll 2
    for (int t = 0; t < 32; ++t) {
        const int gt = h * 32 + t;
        const s16x8 bf = bfr[gt * 64 + l];
        f32x16 acc = __builtin_amdgcn_mfma_f32_32x32x16_bf16(af, bf, zacc, 0, 0, 0);
        #pragma unroll
        for (int r = 0; r < 16; ++r) rowmin[r] = fminf(rowmin[r], acc[r]);
        const float c01 = fminf(acc[0], acc[1]),  c23 = fminf(acc[2], acc[3]);
        const float c45 = fminf(acc[4], acc[5]),  c67 = fminf(acc[6], acc[7]);
        const float c89 = fminf(acc[8], acc[9]),  cab = fminf(acc[10], acc[11]);
        const float ccd = fminf(acc[12], acc[13]), cef = fminf(acc[14], acc[15]);
        float colv = fminf(fminf(fminf(c01, c23), fminf(c45, c67)),
                           fminf(fminf(c89, cab), fminf(ccd, cef)));
        colv = fminf(colv, __shfl_xor(colv, 32));       // other 16 rows
        colpart[w & 3][gt * 32 + cl] = colv;            // dup write l/l+32: benign
    }

    // --- rowmin: reduce over the 32 cols held across lanes of my k-group ---
    #pragma unroll
    for (int mask = 1; mask < 32; mask <<= 1) {
        #pragma unroll
        for (int r = 0; r < 16; ++r)
            rowmin[r] = fminf(rowmin[r], __shfl_xor(rowmin[r], mask));
    }
    if (cl == 0) {
        #pragma unroll
        for (int r = 0; r < 16; ++r) rowpart[w][g][r] = rowmin[r];
    }
    __syncthreads();

    // --- rowsum: min across col-halves (w vs w+4), sum 128 rows ---
    if (tid < MSTRIP) {
        const int sub = tid >> 5, rr = tid & 31;
        const int gg = (rr >> 2) & 1, reg = (rr & 3) | ((rr >> 3) << 2);
        float v = fminf(rowpart[sub][gg][reg], rowpart[sub + 4][gg][reg]);
        #pragma unroll
        for (int off = 32; off > 0; off >>= 1) v += __shfl_down(v, off);
        if ((tid & 63) == 0) rsum_s[tid >> 6] = v;
    }

    // --- colmin: min across the 4 wave-row-groups, store to ws ---
    {
        const float4* c0 = (const float4*)colpart[0];
        const float4* c1 = (const float4*)colpart[1];
        const float4* c2 = (const float4*)colpart[2];
        const float4* c3 = (const float4*)colpart[3];
        const float4 v0 = c0[tid], v1 = c1[tid], v2 = c2[tid], v3 = c3[tid];
        float4 o;
        o.x = fminf(fminf(v0.x, v1.x), fminf(v2.x, v3.x));
        o.y = fminf(fminf(v0.y, v1.y), fminf(v2.y, v3.y));
        o.z = fminf(fminf(v0.z, v1.z), fminf(v2.z, v3.z));
        o.w = fminf(fminf(v0.w, v1.w), fminf(v2.w, v3.w));
        ((float4*)(wscol + (size_t)bid * NPTS))[tid] = o;
    }
    __syncthreads();
    if (tid == 0) wsrow[bid] = rsum_s[0] + rsum_s[1];
}

// reduce: 64 blocks = batch(16) x col-chunk(4 of 512 cols). Coalesced
// float4 reads: min over 16 strips, sum over 512 cols, plus 4 rowsum
// entries, ONE scaled atomicAdd into out[0] (64 atomics total).
__global__ __launch_bounds__(128) void reduce_kernel(
    const float* __restrict__ wscol,
    const float* __restrict__ wsrow,
    float* __restrict__ out)
{
    const int g    = blockIdx.x;       // 0..63
    const int bb   = g >> 2;           // batch
    const int cc   = g & 3;            // col-chunk of 512
    const int tid  = threadIdx.x;      // 0..127
    const int lane = tid & 63;
    __shared__ float s2[2];

    // wscol layout: [bid = bb*16 + s][2048]; this block reads cols
    // [cc*512, cc*512+512) of all 16 strips of batch bb, coalesced.
    const float4* base = (const float4*)(wscol + (size_t)bb * NSTRIP * NPTS
                                               + (size_t)cc * 512);
    float4 m = base[tid];              // strip 0 (512 floats = 128 float4)
    #pragma unroll
    for (int s = 1; s < 16; ++s) {
        const float4 v = base[(size_t)s * (NPTS / 4) + tid];
        m.x = fminf(m.x, v.x); m.y = fminf(m.y, v.y);
        m.z = fminf(m.z, v.z); m.w = fminf(m.w, v.w);
    }
    float acc = (m.x + m.y) + (m.z + m.w);

    #pragma unroll
    for (int off = 32; off > 0; off >>= 1)
        acc += __shfl_down(acc, off);
    if (lane == 0) s2[tid >> 6] = acc;
    __syncthreads();

    if (tid == 0) {
        const float rs = (wsrow[4 * g + 0] + wsrow[4 * g + 1])
                       + (wsrow[4 * g + 2] + wsrow[4 * g + 3]);
        atomicAdd(out, ((s2[0] + s2[1]) + rs) * SCALE);
    }
}

extern "C" void kernel_launch(void* const* d_in, const int* in_sizes, int n_in,
                              void* d_out, int out_size, void* d_ws, size_t ws_size,
                              hipStream_t stream)
{
    const float* pred = (const float*)d_in[0];
    const float* tgt  = (const float*)d_in[1];
    float* out   = (float*)d_out;
    float* wscol = (float*)d_ws;                             // 2 MB
    float* wsrow = (float*)d_ws + (size_t)NBLK * NPTS;       // 256 floats

    chamfer_kernel<<<dim3(NBLK), dim3(512), 0, stream>>>(pred, tgt, wscol, wsrow, out);
    reduce_kernel<<<dim3(64), dim3(128), 0, stream>>>(wscol, wsrow, out);
}